// Round 1
// baseline (163639.246 us; speedup 1.0000x reference)
//
#include <hip/hip_runtime.h>

// ContinuousGRULayer: B=128, T=512, F=128, H=512, ODE_STEPS=2, MAX_DT=1.0
// Round 1: correctness baseline.
//   - convert_weights: f32 -> bf16, transposed + k4-packed into d_ws for
//     coalesced 8B/lane streaming.
//   - cgru_scan: one workgroup (512 threads) per batch row. Thread j owns
//     output neuron j. h_stage and r*h broadcast via LDS. x-part of all three
//     matmuls hoisted to once per timestep (reused by all 8 RK4 evals).

namespace {
constexpr int kB = 128, kT = 512, kF = 128, kH = 512;
constexpr int kFH = kF + kH;

// region offsets in d_ws, in units of ushort4 (8 bytes = 4 bf16)
constexpr int OXZ = 0;
constexpr int OXR = OXZ + (kF / 4) * kH;   // 16384
constexpr int OXG = OXR + (kF / 4) * kH;   // 32768
constexpr int OHZ = OXG + (kF / 4) * kH;   // 49152
constexpr int OHR = OHZ + (kH / 4) * kH;   // 114688
constexpr int OHG = OHR + (kH / 4) * kH;   // 180224
constexpr int OTOT = OHG + (kH / 4) * kH;  // 245760 ushort4 = 1.97 MB
}  // namespace

__device__ __forceinline__ unsigned short f2bf(float f) {
  union { float f; unsigned u; } v; v.f = f;
  unsigned r = (v.u + 0x7FFFu + ((v.u >> 16) & 1u)) >> 16;  // RNE
  return (unsigned short)r;
}
__device__ __forceinline__ float bfLo(unsigned u) {
  union { unsigned u; float f; } v; v.u = u << 16; return v.f;
}
__device__ __forceinline__ float bfHi(unsigned u) {
  union { unsigned u; float f; } v; v.u = u & 0xFFFF0000u; return v.f;
}

// One thread per ushort4 output group: reads 4 consecutive f32 weights from
// row j (cols cbase+4*k4 .. +3), writes bf16x4 at [k4][j] (transposed).
__global__ void convert_weights(const float* __restrict__ Wz,
                                const float* __restrict__ Wr,
                                const float* __restrict__ Wg,
                                ushort4* __restrict__ ws) {
  int tid = blockIdx.x * 256 + threadIdx.x;
  if (tid >= OTOT) return;
  const float* W;
  int cbase, k4, j;
  if (tid < OHZ) {                       // x-part regions, K=128
    int m = tid / ((kF / 4) * kH);
    int local = tid - m * ((kF / 4) * kH);
    W = (m == 0) ? Wz : (m == 1) ? Wr : Wg;
    cbase = 0;
    k4 = local / kH;
    j = local - k4 * kH;
  } else {                               // h-part regions, K=512
    int t2 = tid - OHZ;
    int m = t2 / ((kH / 4) * kH);
    int local = t2 - m * ((kH / 4) * kH);
    W = (m == 0) ? Wz : (m == 1) ? Wr : Wg;
    cbase = kF;
    k4 = local / kH;
    j = local - k4 * kH;
  }
  const float* src = W + j * kFH + cbase + k4 * 4;
  ushort4 o;
  o.x = f2bf(src[0]); o.y = f2bf(src[1]); o.z = f2bf(src[2]); o.w = f2bf(src[3]);
  ws[tid] = o;
}

__global__ __launch_bounds__(kH) void cgru_scan(
    const float* __restrict__ x, const float* __restrict__ td,
    const float* __restrict__ bz, const float* __restrict__ br,
    const float* __restrict__ bg, const uint2* __restrict__ ws,
    float* __restrict__ out) {
  __shared__ __align__(16) float hs[kH];   // current RK4 stage input h
  __shared__ __align__(16) float rh[kH];   // r * h_stage
  __shared__ __align__(16) float xt[kF];   // x_t

  const int b = blockIdx.x;
  const int j = threadIdx.x;

  const uint2* __restrict__ wxz = ws + OXZ;
  const uint2* __restrict__ wxr = ws + OXR;
  const uint2* __restrict__ wxg = ws + OXG;
  const uint2* __restrict__ whz = ws + OHZ;
  const uint2* __restrict__ whr = ws + OHR;
  const uint2* __restrict__ whg = ws + OHG;

  const float bzr = bz[j], brr = br[j], bgr = bg[j];

  float hb = 0.0f;   // committed h for this neuron
  hs[j] = 0.0f;

  for (int t = 0; t < kT; ++t) {
    if (j < kF) xt[j] = x[(b * kT + t) * kF + j];
    __syncthreads();   // xt + (first iter) hs init visible

    // ---- x-part + bias, reused by all 8 evals of this timestep ----
    float az = bzr, ar = brr, ag = bgr;
#pragma unroll
    for (int k4 = 0; k4 < kF / 4; ++k4) {
      const float4 x4 = *reinterpret_cast<const float4*>(&xt[k4 * 4]);
      const uint2 wz4 = wxz[k4 * kH + j];
      const uint2 wr4 = wxr[k4 * kH + j];
      const uint2 wg4 = wxg[k4 * kH + j];
      az = fmaf(bfLo(wz4.x), x4.x, az); az = fmaf(bfHi(wz4.x), x4.y, az);
      az = fmaf(bfLo(wz4.y), x4.z, az); az = fmaf(bfHi(wz4.y), x4.w, az);
      ar = fmaf(bfLo(wr4.x), x4.x, ar); ar = fmaf(bfHi(wr4.x), x4.y, ar);
      ar = fmaf(bfLo(wr4.y), x4.z, ar); ar = fmaf(bfHi(wr4.y), x4.w, ar);
      ag = fmaf(bfLo(wg4.x), x4.x, ag); ag = fmaf(bfHi(wg4.x), x4.y, ag);
      ag = fmaf(bfLo(wg4.y), x4.z, ag); ag = fmaf(bfHi(wg4.y), x4.w, ag);
    }

    const float dtv = fminf(td[b * kT + t], 1.0f) * 0.5f;  // min(td,MAX_DT)/ODE_STEPS
    float hsr = hb;  // this thread's stage-input value (== hs[j])

    for (int step = 0; step < 2; ++step) {
      float kacc = 0.0f;
      for (int s = 0; s < 4; ++s) {
        // ---- z, r dots over hs ----
        float zacc = az, racc = ar;
#pragma unroll 4
        for (int k4 = 0; k4 < kH / 4; ++k4) {
          const float4 h4 = *reinterpret_cast<const float4*>(&hs[k4 * 4]);
          const uint2 wz4 = whz[k4 * kH + j];
          const uint2 wr4 = whr[k4 * kH + j];
          zacc = fmaf(bfLo(wz4.x), h4.x, zacc); zacc = fmaf(bfHi(wz4.x), h4.y, zacc);
          zacc = fmaf(bfLo(wz4.y), h4.z, zacc); zacc = fmaf(bfHi(wz4.y), h4.w, zacc);
          racc = fmaf(bfLo(wr4.x), h4.x, racc); racc = fmaf(bfHi(wr4.x), h4.y, racc);
          racc = fmaf(bfLo(wr4.y), h4.z, racc); racc = fmaf(bfHi(wr4.y), h4.w, racc);
        }
        const float z = 1.0f / (1.0f + __expf(-zacc));
        const float r = 1.0f / (1.0f + __expf(-racc));
        rh[j] = r * hsr;
        __syncthreads();  // all hs reads done; rh visible

        // ---- g dot over rh ----
        float gacc = ag;
#pragma unroll 4
        for (int k4 = 0; k4 < kH / 4; ++k4) {
          const float4 r4 = *reinterpret_cast<const float4*>(&rh[k4 * 4]);
          const uint2 wg4 = whg[k4 * kH + j];
          gacc = fmaf(bfLo(wg4.x), r4.x, gacc); gacc = fmaf(bfHi(wg4.x), r4.y, gacc);
          gacc = fmaf(bfLo(wg4.y), r4.z, gacc); gacc = fmaf(bfHi(wg4.y), r4.w, gacc);
        }
        const float g = tanhf(gacc);
        const float kk = (1.0f - z) * (g - hsr);  // dh/dt at this stage
        kacc += ((s == 1 || s == 2) ? 2.0f : 1.0f) * kk;

        float nxt;
        if (s == 0)      nxt = fmaf(0.5f * dtv, kk, hb);
        else if (s == 1) nxt = fmaf(0.5f * dtv, kk, hb);
        else if (s == 2) nxt = fmaf(dtv, kk, hb);
        else { hb = fmaf(dtv * (1.0f / 6.0f), kacc, hb); nxt = hb; }

        hs[j] = nxt;      // safe: hs reads finished before the barrier above
        hsr = nxt;
        __syncthreads();  // hs (and end of rh reads) visible for next stage
      }
    }

    out[(b * kT + t) * kH + j] = hb;  // coalesced f32 store
    // loop-top barrier protects xt overwrite
  }
}

extern "C" void kernel_launch(void* const* d_in, const int* in_sizes, int n_in,
                              void* d_out, int out_size, void* d_ws, size_t ws_size,
                              hipStream_t stream) {
  const float* x  = (const float*)d_in[0];
  const float* td = (const float*)d_in[1];
  const float* Wz = (const float*)d_in[2];
  const float* bz = (const float*)d_in[3];
  const float* Wr = (const float*)d_in[4];
  const float* br = (const float*)d_in[5];
  const float* Wg = (const float*)d_in[6];
  const float* bg = (const float*)d_in[7];
  float* out = (float*)d_out;

  convert_weights<<<(OTOT + 255) / 256, 256, 0, stream>>>(
      Wz, Wr, Wg, (ushort4*)d_ws);
  cgru_scan<<<kB, kH, 0, stream>>>(
      x, td, bz, br, bg, (const uint2*)d_ws, out);
}

// Round 2
// 49910.843 us; speedup vs baseline: 3.2786x; 3.2786x over previous
//
#include <hip/hip_runtime.h>

// ContinuousGRULayer round 2: gate-split 1024-thread blocks + k8-packed bf16
// weights (16B coalesced loads) + v_dot2_f32_bf16 when available.
//
// Thread j (half 0): z-gate full K, g-gate K-low half, RK4 state commit.
// Thread j+512 (half 1): r-gate full K, rh product, g-gate K-high half.
// 3 barriers per RK4 stage; h/rh/x broadcast via LDS.

namespace {
constexpr int kB = 128, kT = 512, kF = 128, kH = 512, kFH = 640;
// d_ws layout in ushort8 (16B) units: 8 consecutive K-weights of one output
// neuron j, transposed so lane j reads 16B at [slice][j] -> wave-coalesced.
constexpr int XS = (kF / 8) * kH;          // 8192 slices-elems per x-gate
constexpr int HS = (kH / 8) * kH;          // 32768 per h-gate
constexpr int OXZ = 0, OXR = XS, OXG = 2 * XS;
constexpr int OHZ = 3 * XS, OHR = 3 * XS + HS, OHG = 3 * XS + 2 * HS;
constexpr int OTOT = 3 * XS + 3 * HS;      // 122880 * 16B = 1.97 MB
}  // namespace

__device__ __forceinline__ unsigned short f2bf(float f) {
  union { float f; unsigned u; } v; v.f = f;
  return (unsigned short)((v.u + 0x7FFFu + ((v.u >> 16) & 1u)) >> 16);  // RNE
}
__device__ __forceinline__ unsigned pack2(float a, float b) {
  return (unsigned)f2bf(a) | ((unsigned)f2bf(b) << 16);
}
__device__ __forceinline__ float bfLo(unsigned u) {
  union { unsigned u; float f; } v; v.u = u << 16; return v.f;
}
__device__ __forceinline__ float bfHi(unsigned u) {
  union { unsigned u; float f; } v; v.u = u & 0xFFFF0000u; return v.f;
}

#if __has_builtin(__builtin_amdgcn_fdot2_f32_bf16)
#define USE_DOT2 1
typedef __bf16 bf2_t __attribute__((ext_vector_type(2)));
__device__ __forceinline__ float dot2bf(unsigned w, unsigned h, float acc) {
  return __builtin_amdgcn_fdot2_f32_bf16(__builtin_bit_cast(bf2_t, w),
                                         __builtin_bit_cast(bf2_t, h), acc, false);
}
typedef unsigned short sh_t;   // LDS h/rh/x element type (bf16 bits)
#else
#define USE_DOT2 0
typedef float sh_t;
#endif

// ---- weight pre-pack: f32 [H][F+H] -> bf16 k8-transposed regions in d_ws ----
__global__ void convert_weights(const float* __restrict__ Wz,
                                const float* __restrict__ Wr,
                                const float* __restrict__ Wg,
                                uint4* __restrict__ ws) {
  int tid = blockIdx.x * 256 + threadIdx.x;
  if (tid >= OTOT) return;
  const float* W;
  int cbase, p, j;
  if (tid < 3 * XS) {
    int m = tid / XS, l = tid - m * XS;
    W = (m == 0) ? Wz : (m == 1) ? Wr : Wg;
    cbase = 0; p = l / kH; j = l - p * kH;
  } else {
    int t2 = tid - 3 * XS;
    int m = t2 / HS, l = t2 - m * HS;
    W = (m == 0) ? Wz : (m == 1) ? Wr : Wg;
    cbase = kF; p = l / kH; j = l - p * kH;
  }
  const float* s = W + j * kFH + cbase + p * 8;
  uint4 o;
  o.x = pack2(s[0], s[1]); o.y = pack2(s[2], s[3]);
  o.z = pack2(s[4], s[5]); o.w = pack2(s[6], s[7]);
  ws[tid] = o;
}

// N slices of 8 K-elements: weights at wp[p*kH] (16B), h at hp[p*8].
template <int N>
__device__ __forceinline__ float dot_slices(const uint4* __restrict__ wp,
                                            const sh_t* __restrict__ hp,
                                            float acc) {
#if USE_DOT2
#pragma unroll 8
  for (int p = 0; p < N; ++p) {
    const uint4 w = wp[p * kH];
    const uint4 h = *reinterpret_cast<const uint4*>(hp + p * 8);
    acc = dot2bf(w.x, h.x, acc);
    acc = dot2bf(w.y, h.y, acc);
    acc = dot2bf(w.z, h.z, acc);
    acc = dot2bf(w.w, h.w, acc);
  }
#else
#pragma unroll 4
  for (int p = 0; p < N; ++p) {
    const uint4 w = wp[p * kH];
    const float4 h0 = *reinterpret_cast<const float4*>(hp + p * 8);
    const float4 h1 = *reinterpret_cast<const float4*>(hp + p * 8 + 4);
    acc = fmaf(bfLo(w.x), h0.x, acc); acc = fmaf(bfHi(w.x), h0.y, acc);
    acc = fmaf(bfLo(w.y), h0.z, acc); acc = fmaf(bfHi(w.y), h0.w, acc);
    acc = fmaf(bfLo(w.z), h1.x, acc); acc = fmaf(bfHi(w.z), h1.y, acc);
    acc = fmaf(bfLo(w.w), h1.z, acc); acc = fmaf(bfHi(w.w), h1.w, acc);
  }
#endif
  return acc;
}

__device__ __forceinline__ sh_t to_sh(float v) {
#if USE_DOT2
  return f2bf(v);
#else
  return v;
#endif
}
__device__ __forceinline__ float from_sh(sh_t v) {
#if USE_DOT2
  return bfLo((unsigned)v);
#else
  return v;
#endif
}

__global__ __launch_bounds__(1024, 4) void cgru_scan(
    const float* __restrict__ x, const float* __restrict__ td,
    const float* __restrict__ bz, const float* __restrict__ br,
    const float* __restrict__ bg, const uint4* __restrict__ ws,
    float* __restrict__ out) {
  __shared__ __align__(16) sh_t hL[kH];     // stage h
  __shared__ __align__(16) sh_t rhL[kH];    // r * h
  __shared__ __align__(16) sh_t xtL[kF];    // x_t
  __shared__ __align__(16) float gpart[kH]; // half1's g partial

  const int b = blockIdx.x;
  const int tid = threadIdx.x;
  const int j = tid & (kH - 1);
  const int half = tid >> 9;

  const uint4* __restrict__ wxz = ws + OXZ + j;
  const uint4* __restrict__ wxr = ws + OXR + j;
  const uint4* __restrict__ wxg = ws + OXG + j;
  const uint4* __restrict__ whz = ws + OHZ + j;
  const uint4* __restrict__ whr = ws + OHR + j;
  const uint4* __restrict__ whg = ws + OHG + j;

  const float bzv = bz[j], brv = br[j], bgv = bg[j];

  float hb = 0.0f;   // committed h (half0)
  float hsr = 0.0f;  // stage-input h[j] (half0)
  if (half == 0) hL[j] = to_sh(0.0f);

  for (int t = 0; t < kT; ++t) {
    if (tid < kF) xtL[tid] = to_sh(x[(b * kT + t) * kF + tid]);
    __syncthreads();  // xt (+ initial h) visible

    // ---- x-part + bias, reused by all 8 RK4 evals of this timestep ----
    float az = 0.f, ar = 0.f, agp0;
    if (half == 0) {
      az = dot_slices<kF / 8>(wxz, xtL, bzv);
      agp0 = dot_slices<kF / 16>(wxg, xtL, bgv);             // x cols 0..63 + bg
    } else {
      ar = dot_slices<kF / 8>(wxr, xtL, brv);
      agp0 = dot_slices<kF / 16>(wxg + (kF / 16) * kH, xtL + kF / 2, 0.0f);
    }
    const float dtv = fminf(td[b * kT + t], 1.0f) * 0.5f;  // min(td,1)/ODE_STEPS

    float kacc = 0.0f;
    for (int e = 0; e < 8; ++e) {   // 2 ODE steps x 4 RK4 stages
      const int s = e & 3;
      if (s == 0) kacc = 0.0f;

      float z = 0.f;
      if (half == 0) {
        const float zacc = dot_slices<kH / 8>(whz, hL, az);
        z = 1.0f / (1.0f + __expf(-zacc));
      } else {
        const float racc = dot_slices<kH / 8>(whr, hL, ar);
        const float r = 1.0f / (1.0f + __expf(-racc));
        rhL[j] = to_sh(r * from_sh(hL[j]));
      }
      __syncthreads();  // #1: rh visible; all hL reads done

      float gp = dot_slices<kH / 16>(whg + half * (kH / 16) * kH,
                                     rhL + half * (kH / 2), agp0);
      if (half == 1) gpart[j] = gp;
      __syncthreads();  // #2: gpart visible

      if (half == 0) {
        const float g = tanhf(gp + gpart[j]);
        const float kk = (1.0f - z) * (g - hsr);
        kacc += ((s == 1 || s == 2) ? 2.0f : 1.0f) * kk;
        float nxt;
        if (s < 3) {
          nxt = fmaf((s == 2 ? 1.0f : 0.5f) * dtv, kk, hb);
        } else {
          hb = fmaf(dtv * (1.0f / 6.0f), kacc, hb);
          nxt = hb;
        }
        hL[j] = to_sh(nxt);
        hsr = nxt;
      }
      __syncthreads();  // #3: new h visible
    }

    if (half == 0) out[(b * kT + t) * kH + j] = hb;  // coalesced
  }
}

extern "C" void kernel_launch(void* const* d_in, const int* in_sizes, int n_in,
                              void* d_out, int out_size, void* d_ws, size_t ws_size,
                              hipStream_t stream) {
  const float* x  = (const float*)d_in[0];
  const float* td = (const float*)d_in[1];
  const float* Wz = (const float*)d_in[2];
  const float* bz = (const float*)d_in[3];
  const float* Wr = (const float*)d_in[4];
  const float* br = (const float*)d_in[5];
  const float* Wg = (const float*)d_in[6];
  const float* bg = (const float*)d_in[7];
  float* out = (float*)d_out;

  convert_weights<<<(OTOT + 255) / 256, 256, 0, stream>>>(
      Wz, Wr, Wg, (uint4*)d_ws);
  cgru_scan<<<kB, 1024, 0, stream>>>(
      x, td, bz, br, bg, (const uint4*)d_ws, out);
}